// Round 10
// baseline (84.166 us; speedup 1.0000x reference)
//
#include <hip/hip_runtime.h>
#include <cfloat>
#include <cmath>

#define NB     4
#define NPTS   4096
#define NLAT   512
#define RPTS   8                  // i-points per thread
#define CJ     64                 // j-points per block
#define NJC    (NPTS / CJ)        // 64 j-chunks
#define NIH    2                  // i-halves
#define NBLK   (3 * NB * NIH * NJC)   // 1536 blocks
#define NMINS  (3 * NB * NPTS)        // 49152 mins + 1 counter

// ---------------------------------------------------------------------------
// Init: mins = +inf bits, counter = 0. Replaces hipMemsetAsync (tiny fill
// dispatches measured ~39 us on this harness). Re-inits ALL cross-call state
// every call -> deterministic, no leftover-state reliance.
// ---------------------------------------------------------------------------
__global__ __launch_bounds__(256) void k_init(unsigned int* __restrict__ mins)
{
    const int i = blockIdx.x * 256 + threadIdx.x;
    mins[i] = 0xFFFFFFFFu;
    if (i == 0) mins[NMINS] = 0u;
}

// ---------------------------------------------------------------------------
__device__ __forceinline__ float block_sum(float v, float* red)
{
    #pragma unroll
    for (int o = 32; o >= 1; o >>= 1) v += __shfl_xor(v, o);
    const int w = threadIdx.x >> 6;
    __syncthreads();
    if ((threadIdx.x & 63) == 0) red[w] = v;
    __syncthreads();
    return red[0] + red[1] + red[2] + red[3];
}

// ---------------------------------------------------------------------------
// Fused kernel: grid = 1536, block = 256.
//   A-core: mode 0 pred->targ, mode 1 targ->pred, mode 2 pred self-NN.
//   Each thread: 8 i-points in registers (live set ~55 VGPR -> no spills,
//   R8 probe showed default RA at 48 VGPR spilled ~2x VALU traffic).
//   64 LDS-staged transformed j-points; per j-pair-chain 6 fma + 1 min3.
//   Combine: skip-checked uint atomicMin (d >= 0 so uint order == float
//   order; min is order-independent -> deterministic).
//   Tail: last finishing block (device counter election) computes Chamfer
//   means, density std, KL, sizing MSE and writes the scalar loss.
// ---------------------------------------------------------------------------
__global__ __launch_bounds__(256, 4) void k_fused(
    const float* __restrict__ pred_pos,
    const float* __restrict__ targ_pos,
    const float* __restrict__ pred_sizing,
    const float* __restrict__ targ_sizing,
    const float* __restrict__ mu,
    const float* __restrict__ logvar,
    unsigned int* __restrict__ mins /* [3][NB][NPTS] + counter */,
    float* __restrict__ out)
{
    __shared__ float4 lds[CJ];        // 1 KiB
    __shared__ float  red[4];
    __shared__ float  acc2[2];
    __shared__ unsigned int elect;

    const int tid   = threadIdx.x;
    const int jc    = blockIdx.x & (NJC - 1);
    const int ihalf = (blockIdx.x >> 6) & 1;
    const int b     = (blockIdx.x >> 7) & 3;
    const int mode  = blockIdx.x >> 9;

    const float* pts = (mode == 1) ? targ_pos : pred_pos;
    const float* oth = (mode == 0) ? targ_pos : pred_pos;

    // stage + transform j-chunk: o' = (-2ox,-2oy,-2oz,|o|^2)
    if (tid < CJ) {
        const float* ob = oth + ((size_t)b * NPTS + jc * CJ) * 3;
        const float x = ob[3 * tid], y = ob[3 * tid + 1], z = ob[3 * tid + 2];
        const float o2 = fmaf(z, z, fmaf(y, y, x * x));
        lds[tid] = make_float4(-2.f * x, -2.f * y, -2.f * z, o2);
    }

    const float* pb = pts + (size_t)b * NPTS * 3;
    float px[RPTS], py[RPTS], pz[RPTS], acc[RPTS];
    #pragma unroll
    for (int k = 0; k < RPTS; ++k) {
        const float* pp = pb + 3 * (ihalf * 2048 + (k << 8) + tid);
        px[k] = pp[0]; py[k] = pp[1]; pz[k] = pp[2];
        acc[k] = FLT_MAX;
    }
    __syncthreads();

    if (mode != 2) {
        #pragma unroll 2
        for (int j = 0; j < CJ; j += 2) {
            const float4 o1 = lds[j];
            const float4 o2 = lds[j + 1];
            #pragma unroll
            for (int k = 0; k < RPTS; ++k) {
                float t1 = fmaf(o1.x, px[k], o1.w);
                t1 = fmaf(o1.y, py[k], t1);
                t1 = fmaf(o1.z, pz[k], t1);
                float t2 = fmaf(o2.x, px[k], o2.w);
                t2 = fmaf(o2.y, py[k], t2);
                t2 = fmaf(o2.z, pz[k], t2);
                acc[k] = fminf(acc[k], fminf(t1, t2));   // -> v_min3_f32
            }
        }
    } else {
        // self-pair exists in this block iff jc>>5 == ihalf, at chain
        // kself = (jc&31)>>2, for threads with tid>>6 == jc&3, j = tid&63.
        const bool have  = (jc >> 5) == ihalf;
        const int  kself = (jc & 31) >> 2;
        const bool aff   = have && ((tid >> 6) == (jc & 3));
        const int  jself = tid & 63;
        float sx = px[0], sy = py[0], sz = pz[0];
        #pragma unroll
        for (int k = 1; k < RPTS; ++k) {
            sx = (k == kself) ? px[k] : sx;
            sy = (k == kself) ? py[k] : sy;
            sz = (k == kself) ? pz[k] : sz;
        }
        float accf = FLT_MAX;
        #pragma unroll 2
        for (int j = 0; j < CJ; j += 2) {
            const float4 o1 = lds[j];
            const float4 o2 = lds[j + 1];
            #pragma unroll
            for (int k = 0; k < RPTS; ++k) {
                float t1 = fmaf(o1.x, px[k], o1.w);
                t1 = fmaf(o1.y, py[k], t1);
                t1 = fmaf(o1.z, pz[k], t1);
                float t2 = fmaf(o2.x, px[k], o2.w);
                t2 = fmaf(o2.y, py[k], t2);
                t2 = fmaf(o2.z, pz[k], t2);
                acc[k] = fminf(acc[k], fminf(t1, t2));
            }
            float f1 = fmaf(o1.x, sx, o1.w);
            f1 = fmaf(o1.y, sy, f1);
            f1 = fmaf(o1.z, sz, f1);
            f1 = (j == jself) ? FLT_MAX : f1;
            float f2 = fmaf(o2.x, sx, o2.w);
            f2 = fmaf(o2.y, sy, f2);
            f2 = fmaf(o2.z, sz, f2);
            f2 = ((j + 1) == jself) ? FLT_MAX : f2;
            accf = fminf(accf, fminf(f1, f2));
        }
        #pragma unroll
        for (int k = 0; k < RPTS; ++k)
            acc[k] = (aff && k == kself) ? accf : acc[k];
    }

    // skip-checked atomicMin combine
    unsigned int* mb = mins + ((size_t)mode * NB + b) * NPTS + ihalf * 2048;
    #pragma unroll
    for (int k = 0; k < RPTS; ++k) {
        const float p2 = fmaf(pz[k], pz[k], fmaf(py[k], py[k], px[k] * px[k]));
        const float v  = fmaxf(acc[k] + p2, 0.f);   // >=0: uint order == float
        const unsigned int ui = __float_as_uint(v);
        const int idx = (k << 8) + tid;
        if (ui < mb[idx])                  // stale-safe: cur only decreases
            atomicMin(&mb[idx], ui);
    }

    // ---- election: last block to finish runs the finalize tail ----
    __syncthreads();                       // drains each wave's vmcnt
    if (tid == 0) {
        __threadfence();                   // release our atomics
        elect = (atomicAdd(&mins[NMINS], 1u) == (unsigned)(NBLK - 1));
    }
    __syncthreads();
    if (!elect) return;
    __threadfence();                       // acquire: invalidate L1

    float cd_acc = 0.f, dens_acc = 0.f;    // tid 0 only
    for (int bb = 0; bb < NB; ++bb) {
        const uint4* p0 = (const uint4*)(mins + (size_t)0 * NB * NPTS + bb * NPTS);
        const uint4* p1 = (const uint4*)(mins + (size_t)1 * NB * NPTS + bb * NPTS);
        const uint4* p2 = (const uint4*)(mins + (size_t)2 * NB * NPTS + bb * NPTS);
        float s1 = 0.f, s3 = 0.f, q3 = 0.f;
        for (int i = tid; i < NPTS / 4; i += 256) {
            const uint4 a = p0[i], c = p1[i], d = p2[i];
            s1 += __uint_as_float(a.x) + __uint_as_float(a.y)
                + __uint_as_float(a.z) + __uint_as_float(a.w)
                + __uint_as_float(c.x) + __uint_as_float(c.y)
                + __uint_as_float(c.z) + __uint_as_float(c.w);
            const float f0 = __uint_as_float(d.x), f1 = __uint_as_float(d.y);
            const float f2 = __uint_as_float(d.z), f3 = __uint_as_float(d.w);
            s3 += f0 + f1 + f2 + f3;
            q3 += fmaf(f0, f0, fmaf(f1, f1, fmaf(f2, f2, f3 * f3)));
        }
        s1 = block_sum(s1, red);
        s3 = block_sum(s3, red);
        q3 = block_sum(q3, red);
        if (tid == 0) {
            cd_acc += s1 / (float)NPTS;
            const float var = (q3 - s3 * s3 / (float)NPTS) / (float)(NPTS - 1);
            dens_acc += sqrtf(fmaxf(var, 0.f));
        }
    }
    if (tid == 0) { acc2[0] = cd_acc; acc2[1] = dens_acc; }

    float kls = 0.f;
    for (int i = tid; i < NB * NLAT; i += 256) {
        const float lv = logvar[i], m = mu[i];
        kls += 1.f + lv - m * m - expf(lv);
    }
    kls = block_sum(kls, red);

    const float4* ps = (const float4*)pred_sizing;
    const float4* ts = (const float4*)targ_sizing;
    float szs = 0.f;
    for (int i = tid; i < NB * NPTS / 4; i += 256) {
        const float4 a = ps[i], c = ts[i];
        const float d0 = a.x - c.x, d1 = a.y - c.y;
        const float d2 = a.z - c.z, d3 = a.w - c.w;
        szs += fmaf(d0, d0, fmaf(d1, d1, fmaf(d2, d2, d3 * d3)));
    }
    szs = block_sum(szs, red);

    if (tid == 0) {
        const float cd     = acc2[0] / (float)NB;
        const float dens   = acc2[1] / (float)NB;
        const float kl     = -0.5f * kls / (float)(NB * NLAT);
        const float sizing = szs / (float)(NB * NPTS);
        out[0] = cd + 0.001f * kl + 0.1f * dens + 0.05f * sizing;
    }
}

// ---------------------------------------------------------------------------
extern "C" void kernel_launch(void* const* d_in, const int* in_sizes, int n_in,
                              void* d_out, int out_size, void* d_ws, size_t ws_size,
                              hipStream_t stream)
{
    const float* pred_pos    = (const float*)d_in[0];
    const float* pred_sizing = (const float*)d_in[1];
    const float* targ_pos    = (const float*)d_in[2];
    const float* targ_sizing = (const float*)d_in[3];
    const float* mu          = (const float*)d_in[4];
    const float* logvar      = (const float*)d_in[5];

    unsigned int* mins = (unsigned int*)d_ws;   // 3*NB*NPTS u32 + 1 counter

    k_init<<<dim3(NMINS / 256), dim3(256), 0, stream>>>(mins);
    k_fused<<<dim3(NBLK), dim3(256), 0, stream>>>(
        pred_pos, targ_pos, pred_sizing, targ_sizing, mu, logvar,
        mins, (float*)d_out);
}

// Round 11
// 84.037 us; speedup vs baseline: 1.0015x; 1.0015x over previous
//
#include <hip/hip_runtime.h>
#include <cfloat>
#include <cmath>

#define NB     4
#define NPTS   4096
#define NLAT   512
#define RPTS   8                  // i-points per thread
#define CJ     64                 // j-points per block
#define NJC    (NPTS / CJ)        // 64 j-chunks
#define NIH    2                  // i-halves
#define NBLK   (3 * NB * NIH * NJC)   // 1536 blocks
#define NMINS  (3 * NB * NPTS)        // 49152 mins + 1 counter

// ---------------------------------------------------------------------------
// Init: mins = +inf bits, counter = 0. Replaces hipMemsetAsync (tiny fill
// dispatches measured ~39 us on this harness). Re-inits ALL cross-call state
// every call -> deterministic, no leftover-state reliance.
// ---------------------------------------------------------------------------
__global__ __launch_bounds__(256) void k_init(unsigned int* __restrict__ mins)
{
    const int i = blockIdx.x * 256 + threadIdx.x;
    mins[i] = 0xFFFFFFFFu;
    if (i == 0) mins[NMINS] = 0u;
}

// ---------------------------------------------------------------------------
__device__ __forceinline__ float block_sum(float v, float* red)
{
    #pragma unroll
    for (int o = 32; o >= 1; o >>= 1) v += __shfl_xor(v, o);
    const int w = threadIdx.x >> 6;
    __syncthreads();
    if ((threadIdx.x & 63) == 0) red[w] = v;
    __syncthreads();
    return red[0] + red[1] + red[2] + red[3];
}

// ---------------------------------------------------------------------------
// Fused kernel: grid = 1536, block = 256.
//   A-core: mode 0 pred->targ, mode 1 targ->pred, mode 2 pred self-NN.
//   Each thread: 8 i-points in registers (live set ~55 VGPR -> no spills,
//   R8 probe showed default RA at 48 VGPR spilled ~2x VALU traffic).
//   64 LDS-staged transformed j-points; per j-pair-chain 6 fma + 1 min3.
//   Combine: skip-checked uint atomicMin (d >= 0 so uint order == float
//   order; min is order-independent -> deterministic).
//   Tail: last finishing block (device counter election) computes Chamfer
//   means, density std, KL, sizing MSE and writes the scalar loss.
// ---------------------------------------------------------------------------
__global__ __launch_bounds__(256, 4) void k_fused(
    const float* __restrict__ pred_pos,
    const float* __restrict__ targ_pos,
    const float* __restrict__ pred_sizing,
    const float* __restrict__ targ_sizing,
    const float* __restrict__ mu,
    const float* __restrict__ logvar,
    unsigned int* __restrict__ mins /* [3][NB][NPTS] + counter */,
    float* __restrict__ out)
{
    __shared__ float4 lds[CJ];        // 1 KiB
    __shared__ float  red[4];
    __shared__ float  acc2[2];
    __shared__ unsigned int elect;

    const int tid   = threadIdx.x;
    const int jc    = blockIdx.x & (NJC - 1);
    const int ihalf = (blockIdx.x >> 6) & 1;
    const int b     = (blockIdx.x >> 7) & 3;
    const int mode  = blockIdx.x >> 9;

    const float* pts = (mode == 1) ? targ_pos : pred_pos;
    const float* oth = (mode == 0) ? targ_pos : pred_pos;

    // stage + transform j-chunk: o' = (-2ox,-2oy,-2oz,|o|^2)
    if (tid < CJ) {
        const float* ob = oth + ((size_t)b * NPTS + jc * CJ) * 3;
        const float x = ob[3 * tid], y = ob[3 * tid + 1], z = ob[3 * tid + 2];
        const float o2 = fmaf(z, z, fmaf(y, y, x * x));
        lds[tid] = make_float4(-2.f * x, -2.f * y, -2.f * z, o2);
    }

    const float* pb = pts + (size_t)b * NPTS * 3;
    float px[RPTS], py[RPTS], pz[RPTS], acc[RPTS];
    #pragma unroll
    for (int k = 0; k < RPTS; ++k) {
        const float* pp = pb + 3 * (ihalf * 2048 + (k << 8) + tid);
        px[k] = pp[0]; py[k] = pp[1]; pz[k] = pp[2];
        acc[k] = FLT_MAX;
    }
    __syncthreads();

    if (mode != 2) {
        #pragma unroll 2
        for (int j = 0; j < CJ; j += 2) {
            const float4 o1 = lds[j];
            const float4 o2 = lds[j + 1];
            #pragma unroll
            for (int k = 0; k < RPTS; ++k) {
                float t1 = fmaf(o1.x, px[k], o1.w);
                t1 = fmaf(o1.y, py[k], t1);
                t1 = fmaf(o1.z, pz[k], t1);
                float t2 = fmaf(o2.x, px[k], o2.w);
                t2 = fmaf(o2.y, py[k], t2);
                t2 = fmaf(o2.z, pz[k], t2);
                acc[k] = fminf(acc[k], fminf(t1, t2));   // -> v_min3_f32
            }
        }
    } else {
        // self-pair exists in this block iff jc>>5 == ihalf, at chain
        // kself = (jc&31)>>2, for threads with tid>>6 == jc&3, j = tid&63.
        const bool have  = (jc >> 5) == ihalf;
        const int  kself = (jc & 31) >> 2;
        const bool aff   = have && ((tid >> 6) == (jc & 3));
        const int  jself = tid & 63;
        float sx = px[0], sy = py[0], sz = pz[0];
        #pragma unroll
        for (int k = 1; k < RPTS; ++k) {
            sx = (k == kself) ? px[k] : sx;
            sy = (k == kself) ? py[k] : sy;
            sz = (k == kself) ? pz[k] : sz;
        }
        float accf = FLT_MAX;
        #pragma unroll 2
        for (int j = 0; j < CJ; j += 2) {
            const float4 o1 = lds[j];
            const float4 o2 = lds[j + 1];
            #pragma unroll
            for (int k = 0; k < RPTS; ++k) {
                float t1 = fmaf(o1.x, px[k], o1.w);
                t1 = fmaf(o1.y, py[k], t1);
                t1 = fmaf(o1.z, pz[k], t1);
                float t2 = fmaf(o2.x, px[k], o2.w);
                t2 = fmaf(o2.y, py[k], t2);
                t2 = fmaf(o2.z, pz[k], t2);
                acc[k] = fminf(acc[k], fminf(t1, t2));
            }
            float f1 = fmaf(o1.x, sx, o1.w);
            f1 = fmaf(o1.y, sy, f1);
            f1 = fmaf(o1.z, sz, f1);
            f1 = (j == jself) ? FLT_MAX : f1;
            float f2 = fmaf(o2.x, sx, o2.w);
            f2 = fmaf(o2.y, sy, f2);
            f2 = fmaf(o2.z, sz, f2);
            f2 = ((j + 1) == jself) ? FLT_MAX : f2;
            accf = fminf(accf, fminf(f1, f2));
        }
        #pragma unroll
        for (int k = 0; k < RPTS; ++k)
            acc[k] = (aff && k == kself) ? accf : acc[k];
    }

    // skip-checked atomicMin combine
    unsigned int* mb = mins + ((size_t)mode * NB + b) * NPTS + ihalf * 2048;
    #pragma unroll
    for (int k = 0; k < RPTS; ++k) {
        const float p2 = fmaf(pz[k], pz[k], fmaf(py[k], py[k], px[k] * px[k]));
        const float v  = fmaxf(acc[k] + p2, 0.f);   // >=0: uint order == float
        const unsigned int ui = __float_as_uint(v);
        const int idx = (k << 8) + tid;
        if (ui < mb[idx])                  // stale-safe: cur only decreases
            atomicMin(&mb[idx], ui);
    }

    // ---- election: last block to finish runs the finalize tail ----
    __syncthreads();                       // drains each wave's vmcnt
    if (tid == 0) {
        __threadfence();                   // release our atomics
        elect = (atomicAdd(&mins[NMINS], 1u) == (unsigned)(NBLK - 1));
    }
    __syncthreads();
    if (!elect) return;
    __threadfence();                       // acquire: invalidate L1

    float cd_acc = 0.f, dens_acc = 0.f;    // tid 0 only
    for (int bb = 0; bb < NB; ++bb) {
        const uint4* p0 = (const uint4*)(mins + (size_t)0 * NB * NPTS + bb * NPTS);
        const uint4* p1 = (const uint4*)(mins + (size_t)1 * NB * NPTS + bb * NPTS);
        const uint4* p2 = (const uint4*)(mins + (size_t)2 * NB * NPTS + bb * NPTS);
        float s1 = 0.f, s3 = 0.f, q3 = 0.f;
        for (int i = tid; i < NPTS / 4; i += 256) {
            const uint4 a = p0[i], c = p1[i], d = p2[i];
            s1 += __uint_as_float(a.x) + __uint_as_float(a.y)
                + __uint_as_float(a.z) + __uint_as_float(a.w)
                + __uint_as_float(c.x) + __uint_as_float(c.y)
                + __uint_as_float(c.z) + __uint_as_float(c.w);
            const float f0 = __uint_as_float(d.x), f1 = __uint_as_float(d.y);
            const float f2 = __uint_as_float(d.z), f3 = __uint_as_float(d.w);
            s3 += f0 + f1 + f2 + f3;
            q3 += fmaf(f0, f0, fmaf(f1, f1, fmaf(f2, f2, f3 * f3)));
        }
        s1 = block_sum(s1, red);
        s3 = block_sum(s3, red);
        q3 = block_sum(q3, red);
        if (tid == 0) {
            cd_acc += s1 / (float)NPTS;
            const float var = (q3 - s3 * s3 / (float)NPTS) / (float)(NPTS - 1);
            dens_acc += sqrtf(fmaxf(var, 0.f));
        }
    }
    if (tid == 0) { acc2[0] = cd_acc; acc2[1] = dens_acc; }

    float kls = 0.f;
    for (int i = tid; i < NB * NLAT; i += 256) {
        const float lv = logvar[i], m = mu[i];
        kls += 1.f + lv - m * m - expf(lv);
    }
    kls = block_sum(kls, red);

    const float4* ps = (const float4*)pred_sizing;
    const float4* ts = (const float4*)targ_sizing;
    float szs = 0.f;
    for (int i = tid; i < NB * NPTS / 4; i += 256) {
        const float4 a = ps[i], c = ts[i];
        const float d0 = a.x - c.x, d1 = a.y - c.y;
        const float d2 = a.z - c.z, d3 = a.w - c.w;
        szs += fmaf(d0, d0, fmaf(d1, d1, fmaf(d2, d2, d3 * d3)));
    }
    szs = block_sum(szs, red);

    if (tid == 0) {
        const float cd     = acc2[0] / (float)NB;
        const float dens   = acc2[1] / (float)NB;
        const float kl     = -0.5f * kls / (float)(NB * NLAT);
        const float sizing = szs / (float)(NB * NPTS);
        out[0] = cd + 0.001f * kl + 0.1f * dens + 0.05f * sizing;
    }
}

// ---------------------------------------------------------------------------
extern "C" void kernel_launch(void* const* d_in, const int* in_sizes, int n_in,
                              void* d_out, int out_size, void* d_ws, size_t ws_size,
                              hipStream_t stream)
{
    const float* pred_pos    = (const float*)d_in[0];
    const float* pred_sizing = (const float*)d_in[1];
    const float* targ_pos    = (const float*)d_in[2];
    const float* targ_sizing = (const float*)d_in[3];
    const float* mu          = (const float*)d_in[4];
    const float* logvar      = (const float*)d_in[5];

    unsigned int* mins = (unsigned int*)d_ws;   // 3*NB*NPTS u32 + 1 counter

    k_init<<<dim3(NMINS / 256), dim3(256), 0, stream>>>(mins);
    k_fused<<<dim3(NBLK), dim3(256), 0, stream>>>(
        pred_pos, targ_pos, pred_sizing, targ_sizing, mu, logvar,
        mins, (float*)d_out);
}

// Round 12
// 46.793 us; speedup vs baseline: 1.7987x; 1.7960x over previous
//
#include <hip/hip_runtime.h>
#include <cfloat>
#include <cmath>

#define NB     4
#define NPTS   4096
#define NLAT   512
#define RPTS   16                 // i-points per thread (all 4096 per block)
#define CJ     64                 // j-points per block
#define NJC    (NPTS / CJ)        // 64 j-chunks
#define NBLK   (3 * NB * NJC)     // 768 blocks
#define NSUM   194                // 192 fold partials + KL + sizing

// ---------------------------------------------------------------------------
// Node 1: partial nearest-distance mins (R8-verified core).
//   mode 0: pred -> target   mode 1: target -> pred   mode 2: pred self
// grid = 768, block = 256, __launch_bounds__(256,4) -> 128-VGPR budget so the
// ~80-float live set (px/py/pz/acc x16 + temps) stays in VGPRs (R8 probe:
// default RA chose 48 VGPR -> spill traffic). LDS stages 64 transformed
// j-points (o' = (-2o, |o|^2)); per j-pair-chain 6 fma + 1 min3.
// Single-writer partial stores -> no init, no atomics, deterministic.
// Block 0 also zeroes node 2's election counter (node boundary orders it).
// ---------------------------------------------------------------------------
__global__ __launch_bounds__(256, 4) void k_min_dist(
    const float* __restrict__ pred_pos,
    const float* __restrict__ targ_pos,
    float* __restrict__ part_mins /* [3][NB][NJC][NPTS] */,
    unsigned int* __restrict__ counter)
{
    __shared__ float4 lds[CJ];    // 1 KiB

    const int tid  = threadIdx.x;
    const int jc   = blockIdx.x & (NJC - 1);
    const int b    = (blockIdx.x >> 6) & 3;
    const int mode = blockIdx.x >> 8;

    if (blockIdx.x == 0 && tid == 0) *counter = 0u;   // re-init every call

    const float* pts = (mode == 1) ? targ_pos : pred_pos;
    const float* oth = (mode == 0) ? targ_pos : pred_pos;

    // stage + transform j-chunk
    if (tid < CJ) {
        const float* ob = oth + ((size_t)b * NPTS + jc * CJ) * 3;
        const float x = ob[3 * tid], y = ob[3 * tid + 1], z = ob[3 * tid + 2];
        const float o2 = fmaf(z, z, fmaf(y, y, x * x));
        lds[tid] = make_float4(-2.f * x, -2.f * y, -2.f * z, o2);
    }

    const float* pb = pts + (size_t)b * NPTS * 3;
    float px[RPTS], py[RPTS], pz[RPTS], acc[RPTS];
    #pragma unroll
    for (int k = 0; k < RPTS; ++k) {
        const float* pp = pb + 3 * (tid + (k << 8));
        px[k] = pp[0]; py[k] = pp[1]; pz[k] = pp[2];
        acc[k] = FLT_MAX;
    }
    __syncthreads();

    if (mode != 2) {
        #pragma unroll 2
        for (int j = 0; j < CJ; j += 2) {
            const float4 o1 = lds[j];
            const float4 o2 = lds[j + 1];
            #pragma unroll
            for (int k = 0; k < RPTS; ++k) {
                float t1 = fmaf(o1.x, px[k], o1.w);
                t1 = fmaf(o1.y, py[k], t1);
                t1 = fmaf(o1.z, pz[k], t1);
                float t2 = fmaf(o2.x, px[k], o2.w);
                t2 = fmaf(o2.y, py[k], t2);
                t2 = fmaf(o2.z, pz[k], t2);
                acc[k] = fminf(acc[k], fminf(t1, t2));   // -> v_min3_f32
            }
        }
    } else {
        // self-pair: chain kself = jc>>2, threads tid>>6 == jc&3, j = tid&63
        const int  kself = jc >> 2;
        const bool aff   = (tid >> 6) == (jc & 3);
        const int  jself = tid & 63;
        float sx = px[0], sy = py[0], sz = pz[0];
        #pragma unroll
        for (int k = 1; k < RPTS; ++k) {
            sx = (k == kself) ? px[k] : sx;
            sy = (k == kself) ? py[k] : sy;
            sz = (k == kself) ? pz[k] : sz;
        }
        float accf = FLT_MAX;
        #pragma unroll 2
        for (int j = 0; j < CJ; j += 2) {
            const float4 o1 = lds[j];
            const float4 o2 = lds[j + 1];
            #pragma unroll
            for (int k = 0; k < RPTS; ++k) {
                float t1 = fmaf(o1.x, px[k], o1.w);
                t1 = fmaf(o1.y, py[k], t1);
                t1 = fmaf(o1.z, pz[k], t1);
                float t2 = fmaf(o2.x, px[k], o2.w);
                t2 = fmaf(o2.y, py[k], t2);
                t2 = fmaf(o2.z, pz[k], t2);
                acc[k] = fminf(acc[k], fminf(t1, t2));
            }
            float f1 = fmaf(o1.x, sx, o1.w);
            f1 = fmaf(o1.y, sy, f1);
            f1 = fmaf(o1.z, sz, f1);
            f1 = (j == jself) ? FLT_MAX : f1;
            float f2 = fmaf(o2.x, sx, o2.w);
            f2 = fmaf(o2.y, sy, f2);
            f2 = fmaf(o2.z, sz, f2);
            f2 = ((j + 1) == jself) ? FLT_MAX : f2;
            accf = fminf(accf, fminf(f1, f2));
        }
        #pragma unroll
        for (int k = 0; k < RPTS; ++k)
            acc[k] = (aff && k == kself) ? accf : acc[k];
    }

    float* mb = part_mins + (((size_t)mode * NB + b) * NJC + jc) * NPTS;
    #pragma unroll
    for (int k = 0; k < RPTS; ++k) {
        const float p2 = fmaf(pz[k], pz[k], fmaf(py[k], py[k], px[k] * px[k]));
        mb[tid + (k << 8)] = acc[k] + p2;                // coalesced per k
    }
}

// ---------------------------------------------------------------------------
__device__ __forceinline__ float block_sum(float v, float* red)
{
    #pragma unroll
    for (int o = 32; o >= 1; o >>= 1) v += __shfl_xor(v, o);
    const int w = threadIdx.x >> 6;
    __syncthreads();
    if ((threadIdx.x & 63) == 0) red[w] = v;
    __syncthreads();
    return red[0] + red[1] + red[2] + red[3];
}

// ---------------------------------------------------------------------------
// Node 2: fold + KL + sizing, then last-finishing block combines 194 scalars.
// blk<192: fold NJC partials for 256-i slice -> sums/sumsqs[blk]
//          (layout blk = mode*64 + b*16 + slice).
// blk 192: KL partial.  blk 193: sizing partial.
// Election tail (R11-verified visibility pattern, tiny workload): reads the
// 194 scalars and writes the final loss.
// ---------------------------------------------------------------------------
__global__ __launch_bounds__(256) void k_fold_final(
    const float* __restrict__ part_mins,
    const float* __restrict__ pred_sizing,
    const float* __restrict__ targ_sizing,
    const float* __restrict__ mu,
    const float* __restrict__ logvar,
    float* __restrict__ sums /* [194] */,
    float* __restrict__ sumsqs /* [194] */,
    unsigned int* __restrict__ counter,
    float* __restrict__ out)
{
    __shared__ float red[4];
    __shared__ float gs[12], gq[12];
    __shared__ unsigned int elect;
    const int blk = blockIdx.x, tid = threadIdx.x;

    if (blk < 192) {
        const int slice = blk & 15;
        const int b     = (blk >> 4) & 3;
        const int mode  = blk >> 6;
        const float* base = part_mins + ((size_t)mode * NB + b) * NJC * NPTS
                            + slice * 256 + tid;
        float m = FLT_MAX;
        #pragma unroll 8
        for (int jc = 0; jc < NJC; ++jc)
            m = fminf(m, base[(size_t)jc * NPTS]);
        const float s  = block_sum(m, red);
        const float s2 = block_sum(m * m, red);
        if (tid == 0) { sums[blk] = s; sumsqs[blk] = s2; }
    } else if (blk == 192) {
        float kls = 0.f;
        for (int i = tid; i < NB * NLAT; i += 256) {
            const float lv = logvar[i], m = mu[i];
            kls += 1.f + lv - m * m - expf(lv);
        }
        kls = block_sum(kls, red);
        if (tid == 0) { sums[192] = kls; sumsqs[192] = 0.f; }
    } else {
        const float4* ps = (const float4*)pred_sizing;
        const float4* ts = (const float4*)targ_sizing;
        float szs = 0.f;
        #pragma unroll 4
        for (int i = tid; i < NB * NPTS / 4; i += 256) {
            const float4 a = ps[i], c = ts[i];
            const float d0 = a.x - c.x, d1 = a.y - c.y;
            const float d2 = a.z - c.z, d3 = a.w - c.w;
            szs += fmaf(d0, d0, fmaf(d1, d1, fmaf(d2, d2, d3 * d3)));
        }
        szs = block_sum(szs, red);
        if (tid == 0) { sums[193] = szs; sumsqs[193] = 0.f; }
    }

    // ---- election: last block combines the 194 scalars ----
    __syncthreads();
    if (tid == 0) {
        __threadfence();                      // release our sums[] stores
        elect = (atomicAdd(counter, 1u) == (unsigned)(NSUM - 1));
    }
    __syncthreads();
    if (!elect) return;
    __threadfence();                          // acquire others' stores

    float v = 0.f, v2 = 0.f;
    if (tid < 192) { v = sums[tid]; v2 = sumsqs[tid]; }
    #pragma unroll
    for (int o = 1; o < 16; o <<= 1) {
        v  += __shfl_xor(v,  o);
        v2 += __shfl_xor(v2, o);
    }
    if (tid < 192 && (tid & 15) == 0) { gs[tid >> 4] = v; gq[tid >> 4] = v2; }
    __syncthreads();

    if (tid == 0) {
        float cd = 0.f, dens = 0.f;
        for (int b = 0; b < NB; ++b) {
            const float s01 = gs[b] + gs[4 + b];      // p2t + t2p sums
            const float sS  = gs[8 + b];              // self-NN sum
            const float sS2 = gq[8 + b];              // self-NN sumsq
            cd += s01 / (float)NPTS;
            const float var = (sS2 - sS * sS / (float)NPTS) / (float)(NPTS - 1);
            dens += sqrtf(fmaxf(var, 0.f));
        }
        cd   /= (float)NB;
        dens /= (float)NB;
        const float kl     = -0.5f * sums[192] / (float)(NB * NLAT);
        const float sizing = sums[193] / (float)(NB * NPTS);
        out[0] = cd + 0.001f * kl + 0.1f * dens + 0.05f * sizing;
    }
}

// ---------------------------------------------------------------------------
extern "C" void kernel_launch(void* const* d_in, const int* in_sizes, int n_in,
                              void* d_out, int out_size, void* d_ws, size_t ws_size,
                              hipStream_t stream)
{
    const float* pred_pos    = (const float*)d_in[0];
    const float* pred_sizing = (const float*)d_in[1];
    const float* targ_pos    = (const float*)d_in[2];
    const float* targ_sizing = (const float*)d_in[3];
    const float* mu          = (const float*)d_in[4];
    const float* logvar      = (const float*)d_in[5];

    float* part_mins = (float*)d_ws;                             // 12.6 MiB
    float* sums      = part_mins + (size_t)3 * NB * NJC * NPTS;  // 194
    float* sumsqs    = sums + NSUM;                              // 194
    unsigned int* counter = (unsigned int*)(sumsqs + NSUM);      // 1

    k_min_dist<<<dim3(NBLK), dim3(256), 0, stream>>>(
        pred_pos, targ_pos, part_mins, counter);
    k_fold_final<<<dim3(NSUM), dim3(256), 0, stream>>>(
        part_mins, pred_sizing, targ_sizing, mu, logvar,
        sums, sumsqs, counter, (float*)d_out);
}

// Round 13
// 46.071 us; speedup vs baseline: 1.8269x; 1.0157x over previous
//
#include <hip/hip_runtime.h>
#include <cfloat>
#include <cmath>

#define NB     4
#define NPTS   4096
#define NLAT   512
#define RPTS   8                  // i-points per thread (half the row)
#define CJ     64                 // j-points per block
#define NJC    (NPTS / CJ)        // 64 j-chunks
#define NIH    2                  // i-halves -> 1536 blocks = 6 waves/SIMD
#define NBLK   (3 * NB * NIH * NJC)
#define NSUM   194                // 192 fold partials + KL + sizing

// ---------------------------------------------------------------------------
// Node 1: partial nearest-distance mins.
//   mode 0: pred -> target   mode 1: target -> pred   mode 2: pred self
// grid = 1536, block = 256. RPTS=8 -> live set ~44 VGPR (R11-measured, no
// spills) AND 6 waves/SIMD (R8 probe: 6 waves/SIMD ran at 79% VALUBusy vs
// ~3 waves grid-limited before). LDS stages 64 transformed j-points
// (o' = (-2o, |o|^2)); per j-pair-chain 6 fma + 1 min3. Single-writer
// partial stores (each block owns an i-half) -> no init/atomics, determin.
// ---------------------------------------------------------------------------
__global__ __launch_bounds__(256, 4) void k_min_dist(
    const float* __restrict__ pred_pos,
    const float* __restrict__ targ_pos,
    float* __restrict__ part_mins /* [3][NB][NJC][NPTS] */,
    unsigned int* __restrict__ counter)
{
    __shared__ float4 lds[CJ];    // 1 KiB

    const int tid   = threadIdx.x;
    const int jc    = blockIdx.x & (NJC - 1);
    const int ihalf = (blockIdx.x >> 6) & 1;
    const int b     = (blockIdx.x >> 7) & 3;
    const int mode  = blockIdx.x >> 9;

    if (blockIdx.x == 0 && tid == 0) *counter = 0u;   // re-init every call

    const float* pts = (mode == 1) ? targ_pos : pred_pos;
    const float* oth = (mode == 0) ? targ_pos : pred_pos;

    // stage + transform j-chunk
    if (tid < CJ) {
        const float* ob = oth + ((size_t)b * NPTS + jc * CJ) * 3;
        const float x = ob[3 * tid], y = ob[3 * tid + 1], z = ob[3 * tid + 2];
        const float o2 = fmaf(z, z, fmaf(y, y, x * x));
        lds[tid] = make_float4(-2.f * x, -2.f * y, -2.f * z, o2);
    }

    const float* pb = pts + (size_t)b * NPTS * 3;
    float px[RPTS], py[RPTS], pz[RPTS], acc[RPTS];
    #pragma unroll
    for (int k = 0; k < RPTS; ++k) {
        const float* pp = pb + 3 * (ihalf * 2048 + (k << 8) + tid);
        px[k] = pp[0]; py[k] = pp[1]; pz[k] = pp[2];
        acc[k] = FLT_MAX;
    }
    __syncthreads();

    if (mode != 2) {
        #pragma unroll 2
        for (int j = 0; j < CJ; j += 2) {
            const float4 o1 = lds[j];
            const float4 o2 = lds[j + 1];
            #pragma unroll
            for (int k = 0; k < RPTS; ++k) {
                float t1 = fmaf(o1.x, px[k], o1.w);
                t1 = fmaf(o1.y, py[k], t1);
                t1 = fmaf(o1.z, pz[k], t1);
                float t2 = fmaf(o2.x, px[k], o2.w);
                t2 = fmaf(o2.y, py[k], t2);
                t2 = fmaf(o2.z, pz[k], t2);
                acc[k] = fminf(acc[k], fminf(t1, t2));   // -> v_min3_f32
            }
        }
    } else {
        // self-pair (R6-verified): block iff jc>>5 == ihalf, chain
        // kself = (jc&31)>>2, threads tid>>6 == jc&3, j = tid&63.
        const bool have  = (jc >> 5) == ihalf;
        const int  kself = (jc & 31) >> 2;
        const bool aff   = have && ((tid >> 6) == (jc & 3));
        const int  jself = tid & 63;
        float sx = px[0], sy = py[0], sz = pz[0];
        #pragma unroll
        for (int k = 1; k < RPTS; ++k) {
            sx = (k == kself) ? px[k] : sx;
            sy = (k == kself) ? py[k] : sy;
            sz = (k == kself) ? pz[k] : sz;
        }
        float accf = FLT_MAX;
        #pragma unroll 2
        for (int j = 0; j < CJ; j += 2) {
            const float4 o1 = lds[j];
            const float4 o2 = lds[j + 1];
            #pragma unroll
            for (int k = 0; k < RPTS; ++k) {
                float t1 = fmaf(o1.x, px[k], o1.w);
                t1 = fmaf(o1.y, py[k], t1);
                t1 = fmaf(o1.z, pz[k], t1);
                float t2 = fmaf(o2.x, px[k], o2.w);
                t2 = fmaf(o2.y, py[k], t2);
                t2 = fmaf(o2.z, pz[k], t2);
                acc[k] = fminf(acc[k], fminf(t1, t2));
            }
            float f1 = fmaf(o1.x, sx, o1.w);
            f1 = fmaf(o1.y, sy, f1);
            f1 = fmaf(o1.z, sz, f1);
            f1 = (j == jself) ? FLT_MAX : f1;
            float f2 = fmaf(o2.x, sx, o2.w);
            f2 = fmaf(o2.y, sy, f2);
            f2 = fmaf(o2.z, sz, f2);
            f2 = ((j + 1) == jself) ? FLT_MAX : f2;
            accf = fminf(accf, fminf(f1, f2));
        }
        #pragma unroll
        for (int k = 0; k < RPTS; ++k)
            acc[k] = (aff && k == kself) ? accf : acc[k];
    }

    float* mb = part_mins + (((size_t)mode * NB + b) * NJC + jc) * NPTS
                + ihalf * 2048;
    #pragma unroll
    for (int k = 0; k < RPTS; ++k) {
        const float p2 = fmaf(pz[k], pz[k], fmaf(py[k], py[k], px[k] * px[k]));
        mb[(k << 8) + tid] = acc[k] + p2;                // coalesced per k
    }
}

// ---------------------------------------------------------------------------
__device__ __forceinline__ float block_sum(float v, float* red)
{
    #pragma unroll
    for (int o = 32; o >= 1; o >>= 1) v += __shfl_xor(v, o);
    const int w = threadIdx.x >> 6;
    __syncthreads();
    if ((threadIdx.x & 63) == 0) red[w] = v;
    __syncthreads();
    return red[0] + red[1] + red[2] + red[3];
}

// ---------------------------------------------------------------------------
// Node 2 (R12-verified): fold + KL + sizing, election tail combines 194
// scalars and writes the loss.
// ---------------------------------------------------------------------------
__global__ __launch_bounds__(256) void k_fold_final(
    const float* __restrict__ part_mins,
    const float* __restrict__ pred_sizing,
    const float* __restrict__ targ_sizing,
    const float* __restrict__ mu,
    const float* __restrict__ logvar,
    float* __restrict__ sums /* [194] */,
    float* __restrict__ sumsqs /* [194] */,
    unsigned int* __restrict__ counter,
    float* __restrict__ out)
{
    __shared__ float red[4];
    __shared__ float gs[12], gq[12];
    __shared__ unsigned int elect;
    const int blk = blockIdx.x, tid = threadIdx.x;

    if (blk < 192) {
        const int slice = blk & 15;
        const int b     = (blk >> 4) & 3;
        const int mode  = blk >> 6;
        const float* base = part_mins + ((size_t)mode * NB + b) * NJC * NPTS
                            + slice * 256 + tid;
        float m = FLT_MAX;
        #pragma unroll 8
        for (int jc = 0; jc < NJC; ++jc)
            m = fminf(m, base[(size_t)jc * NPTS]);
        const float s  = block_sum(m, red);
        const float s2 = block_sum(m * m, red);
        if (tid == 0) { sums[blk] = s; sumsqs[blk] = s2; }
    } else if (blk == 192) {
        float kls = 0.f;
        for (int i = tid; i < NB * NLAT; i += 256) {
            const float lv = logvar[i], m = mu[i];
            kls += 1.f + lv - m * m - expf(lv);
        }
        kls = block_sum(kls, red);
        if (tid == 0) { sums[192] = kls; sumsqs[192] = 0.f; }
    } else {
        const float4* ps = (const float4*)pred_sizing;
        const float4* ts = (const float4*)targ_sizing;
        float szs = 0.f;
        #pragma unroll 4
        for (int i = tid; i < NB * NPTS / 4; i += 256) {
            const float4 a = ps[i], c = ts[i];
            const float d0 = a.x - c.x, d1 = a.y - c.y;
            const float d2 = a.z - c.z, d3 = a.w - c.w;
            szs += fmaf(d0, d0, fmaf(d1, d1, fmaf(d2, d2, d3 * d3)));
        }
        szs = block_sum(szs, red);
        if (tid == 0) { sums[193] = szs; sumsqs[193] = 0.f; }
    }

    __syncthreads();
    if (tid == 0) {
        __threadfence();
        elect = (atomicAdd(counter, 1u) == (unsigned)(NSUM - 1));
    }
    __syncthreads();
    if (!elect) return;
    __threadfence();

    float v = 0.f, v2 = 0.f;
    if (tid < 192) { v = sums[tid]; v2 = sumsqs[tid]; }
    #pragma unroll
    for (int o = 1; o < 16; o <<= 1) {
        v  += __shfl_xor(v,  o);
        v2 += __shfl_xor(v2, o);
    }
    if (tid < 192 && (tid & 15) == 0) { gs[tid >> 4] = v; gq[tid >> 4] = v2; }
    __syncthreads();

    if (tid == 0) {
        float cd = 0.f, dens = 0.f;
        for (int b = 0; b < NB; ++b) {
            const float s01 = gs[b] + gs[4 + b];
            const float sS  = gs[8 + b];
            const float sS2 = gq[8 + b];
            cd += s01 / (float)NPTS;
            const float var = (sS2 - sS * sS / (float)NPTS) / (float)(NPTS - 1);
            dens += sqrtf(fmaxf(var, 0.f));
        }
        cd   /= (float)NB;
        dens /= (float)NB;
        const float kl     = -0.5f * sums[192] / (float)(NB * NLAT);
        const float sizing = sums[193] / (float)(NB * NPTS);
        out[0] = cd + 0.001f * kl + 0.1f * dens + 0.05f * sizing;
    }
}

// ---------------------------------------------------------------------------
extern "C" void kernel_launch(void* const* d_in, const int* in_sizes, int n_in,
                              void* d_out, int out_size, void* d_ws, size_t ws_size,
                              hipStream_t stream)
{
    const float* pred_pos    = (const float*)d_in[0];
    const float* pred_sizing = (const float*)d_in[1];
    const float* targ_pos    = (const float*)d_in[2];
    const float* targ_sizing = (const float*)d_in[3];
    const float* mu          = (const float*)d_in[4];
    const float* logvar      = (const float*)d_in[5];

    float* part_mins = (float*)d_ws;                             // 12.6 MiB
    float* sums      = part_mins + (size_t)3 * NB * NJC * NPTS;  // 194
    float* sumsqs    = sums + NSUM;                              // 194
    unsigned int* counter = (unsigned int*)(sumsqs + NSUM);      // 1

    k_min_dist<<<dim3(NBLK), dim3(256), 0, stream>>>(
        pred_pos, targ_pos, part_mins, counter);
    k_fold_final<<<dim3(NSUM), dim3(256), 0, stream>>>(
        part_mins, pred_sizing, targ_sizing, mu, logvar,
        sums, sumsqs, counter, (float*)d_out);
}

// Round 14
// 45.764 us; speedup vs baseline: 1.8392x; 1.0067x over previous
//
#include <hip/hip_runtime.h>
#include <cfloat>
#include <cmath>

#define NB     4
#define NPTS   4096
#define NLAT   512
#define RPTS   8                  // i-points per thread (half the row)
#define CJ     64                 // j-points per block
#define NJC    (NPTS / CJ)        // 64 j-chunks
#define NIH    2                  // i-halves -> 1536 blocks = 6 waves/SIMD
#define NBLK   (3 * NB * NIH * NJC)
#define NSUM   194                // 192 fold partials + KL + sizing

// ---------------------------------------------------------------------------
// Node 1: partial nearest-distance mins.
//   mode 0: pred -> target   mode 1: target -> pred   mode 2: pred self
// grid = 1536, block = 256. RPTS=8 -> live set ~44 VGPR (R11-measured, no
// spills) AND 6 waves/SIMD (R8 probe: 6 waves/SIMD ran at 79% VALUBusy vs
// ~3 waves grid-limited before). LDS stages 64 transformed j-points
// (o' = (-2o, |o|^2)); per j-pair-chain 6 fma + 1 min3. Single-writer
// partial stores (each block owns an i-half) -> no init/atomics, determin.
// ---------------------------------------------------------------------------
__global__ __launch_bounds__(256, 4) void k_min_dist(
    const float* __restrict__ pred_pos,
    const float* __restrict__ targ_pos,
    float* __restrict__ part_mins /* [3][NB][NJC][NPTS] */,
    unsigned int* __restrict__ counter)
{
    __shared__ float4 lds[CJ];    // 1 KiB

    const int tid   = threadIdx.x;
    const int jc    = blockIdx.x & (NJC - 1);
    const int ihalf = (blockIdx.x >> 6) & 1;
    const int b     = (blockIdx.x >> 7) & 3;
    const int mode  = blockIdx.x >> 9;

    if (blockIdx.x == 0 && tid == 0) *counter = 0u;   // re-init every call

    const float* pts = (mode == 1) ? targ_pos : pred_pos;
    const float* oth = (mode == 0) ? targ_pos : pred_pos;

    // stage + transform j-chunk
    if (tid < CJ) {
        const float* ob = oth + ((size_t)b * NPTS + jc * CJ) * 3;
        const float x = ob[3 * tid], y = ob[3 * tid + 1], z = ob[3 * tid + 2];
        const float o2 = fmaf(z, z, fmaf(y, y, x * x));
        lds[tid] = make_float4(-2.f * x, -2.f * y, -2.f * z, o2);
    }

    const float* pb = pts + (size_t)b * NPTS * 3;
    float px[RPTS], py[RPTS], pz[RPTS], acc[RPTS];
    #pragma unroll
    for (int k = 0; k < RPTS; ++k) {
        const float* pp = pb + 3 * (ihalf * 2048 + (k << 8) + tid);
        px[k] = pp[0]; py[k] = pp[1]; pz[k] = pp[2];
        acc[k] = FLT_MAX;
    }
    __syncthreads();

    if (mode != 2) {
        #pragma unroll 2
        for (int j = 0; j < CJ; j += 2) {
            const float4 o1 = lds[j];
            const float4 o2 = lds[j + 1];
            #pragma unroll
            for (int k = 0; k < RPTS; ++k) {
                float t1 = fmaf(o1.x, px[k], o1.w);
                t1 = fmaf(o1.y, py[k], t1);
                t1 = fmaf(o1.z, pz[k], t1);
                float t2 = fmaf(o2.x, px[k], o2.w);
                t2 = fmaf(o2.y, py[k], t2);
                t2 = fmaf(o2.z, pz[k], t2);
                acc[k] = fminf(acc[k], fminf(t1, t2));   // -> v_min3_f32
            }
        }
    } else {
        // self-pair (R6-verified): block iff jc>>5 == ihalf, chain
        // kself = (jc&31)>>2, threads tid>>6 == jc&3, j = tid&63.
        const bool have  = (jc >> 5) == ihalf;
        const int  kself = (jc & 31) >> 2;
        const bool aff   = have && ((tid >> 6) == (jc & 3));
        const int  jself = tid & 63;
        float sx = px[0], sy = py[0], sz = pz[0];
        #pragma unroll
        for (int k = 1; k < RPTS; ++k) {
            sx = (k == kself) ? px[k] : sx;
            sy = (k == kself) ? py[k] : sy;
            sz = (k == kself) ? pz[k] : sz;
        }
        float accf = FLT_MAX;
        #pragma unroll 2
        for (int j = 0; j < CJ; j += 2) {
            const float4 o1 = lds[j];
            const float4 o2 = lds[j + 1];
            #pragma unroll
            for (int k = 0; k < RPTS; ++k) {
                float t1 = fmaf(o1.x, px[k], o1.w);
                t1 = fmaf(o1.y, py[k], t1);
                t1 = fmaf(o1.z, pz[k], t1);
                float t2 = fmaf(o2.x, px[k], o2.w);
                t2 = fmaf(o2.y, py[k], t2);
                t2 = fmaf(o2.z, pz[k], t2);
                acc[k] = fminf(acc[k], fminf(t1, t2));
            }
            float f1 = fmaf(o1.x, sx, o1.w);
            f1 = fmaf(o1.y, sy, f1);
            f1 = fmaf(o1.z, sz, f1);
            f1 = (j == jself) ? FLT_MAX : f1;
            float f2 = fmaf(o2.x, sx, o2.w);
            f2 = fmaf(o2.y, sy, f2);
            f2 = fmaf(o2.z, sz, f2);
            f2 = ((j + 1) == jself) ? FLT_MAX : f2;
            accf = fminf(accf, fminf(f1, f2));
        }
        #pragma unroll
        for (int k = 0; k < RPTS; ++k)
            acc[k] = (aff && k == kself) ? accf : acc[k];
    }

    float* mb = part_mins + (((size_t)mode * NB + b) * NJC + jc) * NPTS
                + ihalf * 2048;
    #pragma unroll
    for (int k = 0; k < RPTS; ++k) {
        const float p2 = fmaf(pz[k], pz[k], fmaf(py[k], py[k], px[k] * px[k]));
        mb[(k << 8) + tid] = acc[k] + p2;                // coalesced per k
    }
}

// ---------------------------------------------------------------------------
__device__ __forceinline__ float block_sum(float v, float* red)
{
    #pragma unroll
    for (int o = 32; o >= 1; o >>= 1) v += __shfl_xor(v, o);
    const int w = threadIdx.x >> 6;
    __syncthreads();
    if ((threadIdx.x & 63) == 0) red[w] = v;
    __syncthreads();
    return red[0] + red[1] + red[2] + red[3];
}

// ---------------------------------------------------------------------------
// Node 2 (R12-verified): fold + KL + sizing, election tail combines 194
// scalars and writes the loss.
// ---------------------------------------------------------------------------
__global__ __launch_bounds__(256) void k_fold_final(
    const float* __restrict__ part_mins,
    const float* __restrict__ pred_sizing,
    const float* __restrict__ targ_sizing,
    const float* __restrict__ mu,
    const float* __restrict__ logvar,
    float* __restrict__ sums /* [194] */,
    float* __restrict__ sumsqs /* [194] */,
    unsigned int* __restrict__ counter,
    float* __restrict__ out)
{
    __shared__ float red[4];
    __shared__ float gs[12], gq[12];
    __shared__ unsigned int elect;
    const int blk = blockIdx.x, tid = threadIdx.x;

    if (blk < 192) {
        const int slice = blk & 15;
        const int b     = (blk >> 4) & 3;
        const int mode  = blk >> 6;
        const float* base = part_mins + ((size_t)mode * NB + b) * NJC * NPTS
                            + slice * 256 + tid;
        float m = FLT_MAX;
        #pragma unroll 8
        for (int jc = 0; jc < NJC; ++jc)
            m = fminf(m, base[(size_t)jc * NPTS]);
        const float s  = block_sum(m, red);
        const float s2 = block_sum(m * m, red);
        if (tid == 0) { sums[blk] = s; sumsqs[blk] = s2; }
    } else if (blk == 192) {
        float kls = 0.f;
        for (int i = tid; i < NB * NLAT; i += 256) {
            const float lv = logvar[i], m = mu[i];
            kls += 1.f + lv - m * m - expf(lv);
        }
        kls = block_sum(kls, red);
        if (tid == 0) { sums[192] = kls; sumsqs[192] = 0.f; }
    } else {
        const float4* ps = (const float4*)pred_sizing;
        const float4* ts = (const float4*)targ_sizing;
        float szs = 0.f;
        #pragma unroll 4
        for (int i = tid; i < NB * NPTS / 4; i += 256) {
            const float4 a = ps[i], c = ts[i];
            const float d0 = a.x - c.x, d1 = a.y - c.y;
            const float d2 = a.z - c.z, d3 = a.w - c.w;
            szs += fmaf(d0, d0, fmaf(d1, d1, fmaf(d2, d2, d3 * d3)));
        }
        szs = block_sum(szs, red);
        if (tid == 0) { sums[193] = szs; sumsqs[193] = 0.f; }
    }

    __syncthreads();
    if (tid == 0) {
        __threadfence();
        elect = (atomicAdd(counter, 1u) == (unsigned)(NSUM - 1));
    }
    __syncthreads();
    if (!elect) return;
    __threadfence();

    float v = 0.f, v2 = 0.f;
    if (tid < 192) { v = sums[tid]; v2 = sumsqs[tid]; }
    #pragma unroll
    for (int o = 1; o < 16; o <<= 1) {
        v  += __shfl_xor(v,  o);
        v2 += __shfl_xor(v2, o);
    }
    if (tid < 192 && (tid & 15) == 0) { gs[tid >> 4] = v; gq[tid >> 4] = v2; }
    __syncthreads();

    if (tid == 0) {
        float cd = 0.f, dens = 0.f;
        for (int b = 0; b < NB; ++b) {
            const float s01 = gs[b] + gs[4 + b];
            const float sS  = gs[8 + b];
            const float sS2 = gq[8 + b];
            cd += s01 / (float)NPTS;
            const float var = (sS2 - sS * sS / (float)NPTS) / (float)(NPTS - 1);
            dens += sqrtf(fmaxf(var, 0.f));
        }
        cd   /= (float)NB;
        dens /= (float)NB;
        const float kl     = -0.5f * sums[192] / (float)(NB * NLAT);
        const float sizing = sums[193] / (float)(NB * NPTS);
        out[0] = cd + 0.001f * kl + 0.1f * dens + 0.05f * sizing;
    }
}

// ---------------------------------------------------------------------------
extern "C" void kernel_launch(void* const* d_in, const int* in_sizes, int n_in,
                              void* d_out, int out_size, void* d_ws, size_t ws_size,
                              hipStream_t stream)
{
    const float* pred_pos    = (const float*)d_in[0];
    const float* pred_sizing = (const float*)d_in[1];
    const float* targ_pos    = (const float*)d_in[2];
    const float* targ_sizing = (const float*)d_in[3];
    const float* mu          = (const float*)d_in[4];
    const float* logvar      = (const float*)d_in[5];

    float* part_mins = (float*)d_ws;                             // 12.6 MiB
    float* sums      = part_mins + (size_t)3 * NB * NJC * NPTS;  // 194
    float* sumsqs    = sums + NSUM;                              // 194
    unsigned int* counter = (unsigned int*)(sumsqs + NSUM);      // 1

    k_min_dist<<<dim3(NBLK), dim3(256), 0, stream>>>(
        pred_pos, targ_pos, part_mins, counter);
    k_fold_final<<<dim3(NSUM), dim3(256), 0, stream>>>(
        part_mins, pred_sizing, targ_sizing, mu, logvar,
        sums, sumsqs, counter, (float*)d_out);
}

// Round 16
// 40.111 us; speedup vs baseline: 2.0983x; 1.1409x over previous
//
#include <hip/hip_runtime.h>
#include <cfloat>
#include <cmath>

#define NB     4
#define NPTS   4096
#define NLAT   512
#define RPTS   4                  // i-points per thread
#define CJ     128                // j-points per block
#define NJC    (NPTS / CJ)        // 32 j-chunks
#define NIH    4                  // i-quarters -> 1536 blocks, 6 waves/SIMD
#define NBLK   (3 * NB * NIH * NJC)   // 1536
#define NSUM   194                // 192 fold partials + KL + sizing

// ---------------------------------------------------------------------------
// Node 1: partial nearest-distance mins.
//   mode 0: pred -> target   mode 1: target -> pred   mode 2: pred self
// grid = 1536, block = 256. CJ=128/RPTS=4/NIH=4: partials 6.3 MB (half of
// R14), live set ~28 VGPR, 6 waves/SIMD. LDS stages 128 transformed
// j-points (o' = (-2o, |o|^2)); per j-pair-chain 6 fma + 1 min3.
// Single-writer partial stores -> no init/atomics, deterministic.
// Self-pair mapping (hand-verified: i=1500 -> jc=11, iq=1, k=1, tid=220):
// block iff jc>>3 == iq; kself=(jc>>1)&3; aff iff tid>>7 == jc&1; jself=tid&127.
// ---------------------------------------------------------------------------
__global__ __launch_bounds__(256, 4) void k_min_dist(
    const float* __restrict__ pred_pos,
    const float* __restrict__ targ_pos,
    float* __restrict__ part_mins /* [3][NB][NJC][NPTS] */,
    unsigned int* __restrict__ counter)
{
    __shared__ float4 lds[CJ];    // 2 KiB

    const int tid  = threadIdx.x;
    const int blk  = blockIdx.x;
    const int jc   = blk & (NJC - 1);
    const int iq   = (blk >> 5) & 3;
    const int b    = (blk >> 7) & 3;
    const int mode = blk >> 9;

    if (blk == 0 && tid == 0) *counter = 0u;   // re-init every call

    const float* pts = (mode == 1) ? targ_pos : pred_pos;
    const float* oth = (mode == 0) ? targ_pos : pred_pos;

    // stage + transform j-chunk
    if (tid < CJ) {
        const float* ob = oth + ((size_t)b * NPTS + jc * CJ) * 3;
        const float x = ob[3 * tid], y = ob[3 * tid + 1], z = ob[3 * tid + 2];
        const float o2 = fmaf(z, z, fmaf(y, y, x * x));
        lds[tid] = make_float4(-2.f * x, -2.f * y, -2.f * z, o2);
    }

    const float* pb = pts + (size_t)b * NPTS * 3;
    float px[RPTS], py[RPTS], pz[RPTS], acc[RPTS];
    #pragma unroll
    for (int k = 0; k < RPTS; ++k) {
        const float* pp = pb + 3 * (iq * 1024 + (k << 8) + tid);
        px[k] = pp[0]; py[k] = pp[1]; pz[k] = pp[2];
        acc[k] = FLT_MAX;
    }
    __syncthreads();

    if (mode != 2) {
        #pragma unroll 2
        for (int j = 0; j < CJ; j += 2) {
            const float4 o1 = lds[j];
            const float4 o2 = lds[j + 1];
            #pragma unroll
            for (int k = 0; k < RPTS; ++k) {
                float t1 = fmaf(o1.x, px[k], o1.w);
                t1 = fmaf(o1.y, py[k], t1);
                t1 = fmaf(o1.z, pz[k], t1);
                float t2 = fmaf(o2.x, px[k], o2.w);
                t2 = fmaf(o2.y, py[k], t2);
                t2 = fmaf(o2.z, pz[k], t2);
                acc[k] = fminf(acc[k], fminf(t1, t2));   // -> v_min3_f32
            }
        }
    } else {
        const bool have  = (jc >> 3) == iq;
        const int  kself = (jc >> 1) & 3;
        const bool aff   = have && ((tid >> 7) == (jc & 1));
        const int  jself = tid & 127;
        float sx = px[0], sy = py[0], sz = pz[0];
        #pragma unroll
        for (int k = 1; k < RPTS; ++k) {
            sx = (k == kself) ? px[k] : sx;
            sy = (k == kself) ? py[k] : sy;
            sz = (k == kself) ? pz[k] : sz;
        }
        float accf = FLT_MAX;
        #pragma unroll 2
        for (int j = 0; j < CJ; j += 2) {
            const float4 o1 = lds[j];
            const float4 o2 = lds[j + 1];
            #pragma unroll
            for (int k = 0; k < RPTS; ++k) {
                float t1 = fmaf(o1.x, px[k], o1.w);
                t1 = fmaf(o1.y, py[k], t1);
                t1 = fmaf(o1.z, pz[k], t1);
                float t2 = fmaf(o2.x, px[k], o2.w);
                t2 = fmaf(o2.y, py[k], t2);
                t2 = fmaf(o2.z, pz[k], t2);
                acc[k] = fminf(acc[k], fminf(t1, t2));
            }
            float f1 = fmaf(o1.x, sx, o1.w);
            f1 = fmaf(o1.y, sy, f1);
            f1 = fmaf(o1.z, sz, f1);
            f1 = (j == jself) ? FLT_MAX : f1;
            float f2 = fmaf(o2.x, sx, o2.w);
            f2 = fmaf(o2.y, sy, f2);
            f2 = fmaf(o2.z, sz, f2);
            f2 = ((j + 1) == jself) ? FLT_MAX : f2;
            accf = fminf(accf, fminf(f1, f2));
        }
        #pragma unroll
        for (int k = 0; k < RPTS; ++k)
            acc[k] = (aff && k == kself) ? accf : acc[k];
    }

    float* mb = part_mins + (((size_t)mode * NB + b) * NJC + jc) * NPTS
                + iq * 1024;
    #pragma unroll
    for (int k = 0; k < RPTS; ++k) {
        const float p2 = fmaf(pz[k], pz[k], fmaf(py[k], py[k], px[k] * px[k]));
        mb[(k << 8) + tid] = acc[k] + p2;                // coalesced per k
    }
}

// ---------------------------------------------------------------------------
__device__ __forceinline__ float block_sum(float v, float* red)
{
    #pragma unroll
    for (int o = 32; o >= 1; o >>= 1) v += __shfl_xor(v, o);
    const int w = threadIdx.x >> 6;
    __syncthreads();
    if ((threadIdx.x & 63) == 0) red[w] = v;
    __syncthreads();
    return red[0] + red[1] + red[2] + red[3];
}

// ---------------------------------------------------------------------------
// Node 2 (R12/R14-verified): fold + KL + sizing, election tail combines 194
// scalars and writes the loss.
// ---------------------------------------------------------------------------
__global__ __launch_bounds__(256) void k_fold_final(
    const float* __restrict__ part_mins,
    const float* __restrict__ pred_sizing,
    const float* __restrict__ targ_sizing,
    const float* __restrict__ mu,
    const float* __restrict__ logvar,
    float* __restrict__ sums /* [194] */,
    float* __restrict__ sumsqs /* [194] */,
    unsigned int* __restrict__ counter,
    float* __restrict__ out)
{
    __shared__ float red[4];
    __shared__ float gs[12], gq[12];
    __shared__ unsigned int elect;
    const int blk = blockIdx.x, tid = threadIdx.x;

    if (blk < 192) {
        const int slice = blk & 15;
        const int b     = (blk >> 4) & 3;
        const int mode  = blk >> 6;
        const float* base = part_mins + ((size_t)mode * NB + b) * NJC * NPTS
                            + slice * 256 + tid;
        float m = FLT_MAX;
        #pragma unroll 8
        for (int jc = 0; jc < NJC; ++jc)
            m = fminf(m, base[(size_t)jc * NPTS]);
        const float s  = block_sum(m, red);
        const float s2 = block_sum(m * m, red);
        if (tid == 0) { sums[blk] = s; sumsqs[blk] = s2; }
    } else if (blk == 192) {
        float kls = 0.f;
        for (int i = tid; i < NB * NLAT; i += 256) {
            const float lv = logvar[i], m = mu[i];
            kls += 1.f + lv - m * m - expf(lv);
        }
        kls = block_sum(kls, red);
        if (tid == 0) { sums[192] = kls; sumsqs[192] = 0.f; }
    } else {
        const float4* ps = (const float4*)pred_sizing;
        const float4* ts = (const float4*)targ_sizing;
        float szs = 0.f;
        #pragma unroll 4
        for (int i = tid; i < NB * NPTS / 4; i += 256) {
            const float4 a = ps[i], c = ts[i];
            const float d0 = a.x - c.x, d1 = a.y - c.y;
            const float d2 = a.z - c.z, d3 = a.w - c.w;
            szs += fmaf(d0, d0, fmaf(d1, d1, fmaf(d2, d2, d3 * d3)));
        }
        szs = block_sum(szs, red);
        if (tid == 0) { sums[193] = szs; sumsqs[193] = 0.f; }
    }

    __syncthreads();
    if (tid == 0) {
        __threadfence();
        elect = (atomicAdd(counter, 1u) == (unsigned)(NSUM - 1));
    }
    __syncthreads();
    if (!elect) return;
    __threadfence();

    float v = 0.f, v2 = 0.f;
    if (tid < 192) { v = sums[tid]; v2 = sumsqs[tid]; }
    #pragma unroll
    for (int o = 1; o < 16; o <<= 1) {
        v  += __shfl_xor(v,  o);
        v2 += __shfl_xor(v2, o);
    }
    if (tid < 192 && (tid & 15) == 0) { gs[tid >> 4] = v; gq[tid >> 4] = v2; }
    __syncthreads();

    if (tid == 0) {
        float cd = 0.f, dens = 0.f;
        for (int b = 0; b < NB; ++b) {
            const float s01 = gs[b] + gs[4 + b];
            const float sS  = gs[8 + b];
            const float sS2 = gq[8 + b];
            cd += s01 / (float)NPTS;
            const float var = (sS2 - sS * sS / (float)NPTS) / (float)(NPTS - 1);
            dens += sqrtf(fmaxf(var, 0.f));
        }
        cd   /= (float)NB;
        dens /= (float)NB;
        const float kl     = -0.5f * sums[192] / (float)(NB * NLAT);
        const float sizing = sums[193] / (float)(NB * NPTS);
        out[0] = cd + 0.001f * kl + 0.1f * dens + 0.05f * sizing;
    }
}

// ---------------------------------------------------------------------------
extern "C" void kernel_launch(void* const* d_in, const int* in_sizes, int n_in,
                              void* d_out, int out_size, void* d_ws, size_t ws_size,
                              hipStream_t stream)
{
    const float* pred_pos    = (const float*)d_in[0];
    const float* pred_sizing = (const float*)d_in[1];
    const float* targ_pos    = (const float*)d_in[2];
    const float* targ_sizing = (const float*)d_in[3];
    const float* mu          = (const float*)d_in[4];
    const float* logvar      = (const float*)d_in[5];

    float* part_mins = (float*)d_ws;                             // 6.3 MiB
    float* sums      = part_mins + (size_t)3 * NB * NJC * NPTS;  // 194
    float* sumsqs    = sums + NSUM;                              // 194
    unsigned int* counter = (unsigned int*)(sumsqs + NSUM);      // 1

    k_min_dist<<<dim3(NBLK), dim3(256), 0, stream>>>(
        pred_pos, targ_pos, part_mins, counter);
    k_fold_final<<<dim3(NSUM), dim3(256), 0, stream>>>(
        part_mins, pred_sizing, targ_sizing, mu, logvar,
        sums, sumsqs, counter, (float*)d_out);
}